// Round 1
// baseline (478.942 us; speedup 1.0000x reference)
//
#include <hip/hip_runtime.h>
#include <math.h>

// SpectralPooling: out[b,c,nd,nh,w] = sum_{d,h} A[nd,d]*A[nh,h]*x[b,c,d,h,w]  (w<32)
// where A = C32^T @ C64[:32,:] (32x64). The B-axis forward+inverse 8-pt DCT is
// C8^T C8 = I (orthonormal) and is skipped exactly.

__global__ void build_A_kernel(float* __restrict__ A, float* __restrict__ At) {
  int idx = blockIdx.x * blockDim.x + threadIdx.x;
  if (idx >= 32 * 64) return;
  int n = idx >> 6;   // 0..31 output freq
  int h = idx & 63;   // 0..63 spatial
  double s = 0.0;
  for (int k = 0; k < 32; ++k) {
    double s32 = (k == 0) ? sqrt(1.0 / 32.0) : sqrt(2.0 / 32.0);
    double s64 = (k == 0) ? sqrt(1.0 / 64.0) : sqrt(2.0 / 64.0);
    double c32 = cos(M_PI * ((double)n + 0.5) * (double)k / 32.0) * s32;
    double c64 = cos(M_PI * ((double)h + 0.5) * (double)k / 64.0) * s64;
    s += c32 * c64;
  }
  A[n * 64 + h] = (float)s;    // A[n][h], rows contiguous (stage-1 scalar loads)
  At[h * 32 + n] = (float)s;   // At[h][n] transposed (stage-2 scalar loads)
}

// One workgroup per (b,c). 512 threads = 8 waves.
// Stage 1 lanes: (dloc = lane>>5, w = lane&31); wave wv covers d = chunk*16 + 2*wv + dloc.
//   Each lane holds x[b,c,d,:,w] (64 h) in VGPRs; A row is wave-uniform -> SGPR.
// Stage 2 lanes: (nd8 = wave, nh4 = (tid>>4)&3, w16 = tid&15); acc[4 nd][2 half][4 nh][2 w].
__global__ __launch_bounds__(512, 2) void spectral_kernel(
    const float* __restrict__ x, const float* __restrict__ A,
    const float* __restrict__ At, float* __restrict__ out) {
  __shared__ float V[16][16][34];  // [d_in_chunk][nh_in_half][w pad->34] = 34.8 KB

  const int tid = threadIdx.x;
  const int bc = blockIdx.x;          // b*32 + c
  const int wv = tid >> 6;            // wave id, 0..7 (wave-uniform)
  const int dloc = (tid >> 5) & 1;
  const int w = tid & 31;
  const int nh4 = (tid >> 4) & 3;     // stage-2 nh group
  const int w16 = tid & 15;           // stage-2 w pair

  const float* xb = x + (size_t)bc * 262144;  // 64*64*64

  float acc[4][2][4][2];
  #pragma unroll
  for (int i = 0; i < 4; ++i)
    #pragma unroll
    for (int hf = 0; hf < 2; ++hf)
      #pragma unroll
      for (int j = 0; j < 4; ++j) {
        acc[i][hf][j][0] = 0.f;
        acc[i][hf][j][1] = 0.f;
      }

  #pragma unroll 1
  for (int cc = 0; cc < 4; ++cc) {
    // ---- load this wave's two X columns: xr[h] = x[bc, d, h, w]
    const int d = cc * 16 + wv * 2 + dloc;
    const float* xcol = xb + (size_t)d * 4096 + w;
    float xr[64];
    #pragma unroll
    for (int h = 0; h < 64; ++h) xr[h] = xcol[h * 64];

    #pragma unroll 1
    for (int half = 0; half < 2; ++half) {
      // ---- stage 1: V[d][nh][w] = sum_h A[nh,h] * xr[h]  (A wave-uniform -> s_load)
      #pragma unroll 1
      for (int nh = 0; nh < 16; ++nh) {
        const float* Arow = A + (half * 16 + nh) * 64;
        float p0 = 0.f, p1 = 0.f, p2 = 0.f, p3 = 0.f;
        #pragma unroll
        for (int h = 0; h < 64; h += 4) {
          p0 = fmaf(Arow[h + 0], xr[h + 0], p0);
          p1 = fmaf(Arow[h + 1], xr[h + 1], p1);
          p2 = fmaf(Arow[h + 2], xr[h + 2], p2);
          p3 = fmaf(Arow[h + 3], xr[h + 3], p3);
        }
        V[wv * 2 + dloc][nh][w] = (p0 + p1) + (p2 + p3);
      }
      __syncthreads();

      // ---- stage 2: acc[nd][..] += At[d][nd] * V[d][nh][w]  (At wave-uniform -> s_load)
      #pragma unroll 1
      for (int dd = 0; dd < 16; ++dd) {
        const int dg = cc * 16 + dd;
        const float* Acol = At + dg * 32 + wv * 4;  // 4 nd values, wave-uniform
        const float a0 = Acol[0], a1 = Acol[1], a2 = Acol[2], a3 = Acol[3];
        #pragma unroll
        for (int j = 0; j < 4; ++j) {
          const float v0 = V[dd][nh4 * 4 + j][w16 * 2 + 0];
          const float v1 = V[dd][nh4 * 4 + j][w16 * 2 + 1];
          acc[0][half][j][0] = fmaf(a0, v0, acc[0][half][j][0]);
          acc[0][half][j][1] = fmaf(a0, v1, acc[0][half][j][1]);
          acc[1][half][j][0] = fmaf(a1, v0, acc[1][half][j][0]);
          acc[1][half][j][1] = fmaf(a1, v1, acc[1][half][j][1]);
          acc[2][half][j][0] = fmaf(a2, v0, acc[2][half][j][0]);
          acc[2][half][j][1] = fmaf(a2, v1, acc[2][half][j][1]);
          acc[3][half][j][0] = fmaf(a3, v0, acc[3][half][j][0]);
          acc[3][half][j][1] = fmaf(a3, v1, acc[3][half][j][1]);
        }
      }
      __syncthreads();
    }
  }

  // ---- epilogue: out[bc, nd, nh, w], float2 stores, coalesced across (nh4,w16)
  float* ob = out + (size_t)bc * 32768;
  #pragma unroll
  for (int i = 0; i < 4; ++i) {
    const int nd = wv * 4 + i;
    #pragma unroll
    for (int hf = 0; hf < 2; ++hf) {
      #pragma unroll
      for (int j = 0; j < 4; ++j) {
        const int nh = hf * 16 + nh4 * 4 + j;
        float2 v;
        v.x = acc[i][hf][j][0];
        v.y = acc[i][hf][j][1];
        *(float2*)(ob + nd * 1024 + nh * 32 + w16 * 2) = v;
      }
    }
  }
}

extern "C" void kernel_launch(void* const* d_in, const int* in_sizes, int n_in,
                              void* d_out, int out_size, void* d_ws, size_t ws_size,
                              hipStream_t stream) {
  const float* x = (const float*)d_in[0];
  float* A = (float*)d_ws;          // 32*64 floats
  float* At = A + 2048;             // 64*32 floats
  build_A_kernel<<<2, 1024, 0, stream>>>(A, At);
  spectral_kernel<<<256, 512, 0, stream>>>(x, A, At, (float*)d_out);
}

// Round 2
// 382.709 us; speedup vs baseline: 1.2515x; 1.2515x over previous
//
#include <hip/hip_runtime.h>
#include <math.h>

// SpectralPooling: out[b,c,nd,nh,w] = sum_{d,h} A[nd,d]*A[nh,h]*x[b,c,d,h,w]  (w<32)
// where A = C32^T @ C64[:32,:] (32x64). The B-axis forward+inverse 8-pt DCT is
// C8^T C8 = I (orthonormal) and is skipped exactly.

__global__ void build_A_kernel(float* __restrict__ A, float* __restrict__ At) {
  int idx = blockIdx.x * blockDim.x + threadIdx.x;
  if (idx >= 32 * 64) return;
  int n = idx >> 6;   // 0..31 output freq
  int h = idx & 63;   // 0..63 spatial
  // fp32 transcendentals: ~1e-6 abs error in A, far below the 0.104 threshold.
  // (fp64 cos here cost ~300us on 2 blocks in R1.)
  const float s32a = sqrtf(1.0f / 32.0f), s32b = sqrtf(2.0f / 32.0f);
  const float s64a = sqrtf(1.0f / 64.0f), s64b = sqrtf(2.0f / 64.0f);
  float s = 0.0f;
  for (int k = 0; k < 32; ++k) {
    float c32 = cosf((float)M_PI * ((float)n + 0.5f) * (float)k / 32.0f) * ((k == 0) ? s32a : s32b);
    float c64 = cosf((float)M_PI * ((float)h + 0.5f) * (float)k / 64.0f) * ((k == 0) ? s64a : s64b);
    s = fmaf(c32, c64, s);
  }
  A[n * 64 + h] = s;    // A[n][h], rows contiguous (stage-1 scalar loads)
  At[h * 32 + n] = s;   // At[h][n] transposed (stage-2 scalar loads)
}

// One workgroup per (b,c). 512 threads = 8 waves, 2 blocks/CU (64KB LDS, <=128 VGPR).
// Stage 1: lane -> (dloc = (tid>>5)&1, w = tid&31); wave wv covers d = cc*16 + wv*2 + dloc.
//   Stream x over h in chunks of 8 (xr[8]); accumulate p[32] (all nh) in regs.
//   No xr[64] monster array -> no scratch spill (R1's 196MB WRITE_SIZE was spill traffic).
// Stage 2: lane -> (nhq = (tid>>4)&3, w16 = tid&15); wave wv covers nd = wv*4+i.
//   acc[4 nd][8 nh][2 w] = 64 regs, At column wave-uniform -> scalar operand.
__global__ __launch_bounds__(512, 4) void spectral_kernel(
    const float* __restrict__ x, const float* __restrict__ A,
    const float* __restrict__ At, float* __restrict__ out) {
  __shared__ float V[16][32][32];  // 64 KB exactly; [d_chunk][nh][w]

  const int tid = threadIdx.x;
  const int bc = blockIdx.x;          // b*32 + c
  const int wv = tid >> 6;            // wave id 0..7 (wave-uniform)
  const int dloc = (tid >> 5) & 1;
  const int w = tid & 31;
  const int nhq = (tid >> 4) & 3;     // stage-2 nh sub-index
  const int w16 = tid & 15;           // stage-2 w pair

  const float* xb = x + (size_t)bc * 262144;  // 64*64*64

  float acc[4][8][2];
  #pragma unroll
  for (int i = 0; i < 4; ++i)
    #pragma unroll
    for (int j = 0; j < 8; ++j) {
      acc[i][j][0] = 0.f;
      acc[i][j][1] = 0.f;
    }

  #pragma unroll 1
  for (int cc = 0; cc < 4; ++cc) {
    const int d = cc * 16 + wv * 2 + dloc;
    const float* xcol = xb + (size_t)d * 4096 + w;

    // ---- stage 1: p[nh] = sum_h A[nh,h] * x[d,h,w], h streamed in chunks of 8
    float p[32];
    #pragma unroll
    for (int nh = 0; nh < 32; ++nh) p[nh] = 0.f;

    #pragma unroll 1
    for (int hc = 0; hc < 8; ++hc) {
      float xr[8];
      #pragma unroll
      for (int i = 0; i < 8; ++i) xr[i] = xcol[(hc * 8 + i) * 64];
      #pragma unroll
      for (int nh = 0; nh < 32; ++nh) {
        const float* Arow = A + nh * 64 + hc * 8;  // wave-uniform -> s_load
        float q0 = fmaf(Arow[0], xr[0], fmaf(Arow[1], xr[1], 0.f));
        float q1 = fmaf(Arow[2], xr[2], fmaf(Arow[3], xr[3], 0.f));
        float q2 = fmaf(Arow[4], xr[4], fmaf(Arow[5], xr[5], 0.f));
        float q3 = fmaf(Arow[6], xr[6], fmaf(Arow[7], xr[7], 0.f));
        p[nh] += (q0 + q1) + (q2 + q3);
      }
    }
    #pragma unroll
    for (int nh = 0; nh < 32; ++nh) V[wv * 2 + dloc][nh][w] = p[nh];
    __syncthreads();

    // ---- stage 2: acc[nd][nh][w] += At[d][nd] * V[d][nh][w]
    #pragma unroll 1
    for (int dd = 0; dd < 16; ++dd) {
      const int dg = cc * 16 + dd;
      const float* Acol = At + dg * 32 + wv * 4;  // wave-uniform -> s_load_dwordx4
      const float a0 = Acol[0], a1 = Acol[1], a2 = Acol[2], a3 = Acol[3];
      #pragma unroll
      for (int j = 0; j < 8; ++j) {
        const float v0 = V[dd][j * 4 + nhq][w16 * 2 + 0];
        const float v1 = V[dd][j * 4 + nhq][w16 * 2 + 1];
        acc[0][j][0] = fmaf(a0, v0, acc[0][j][0]);
        acc[0][j][1] = fmaf(a0, v1, acc[0][j][1]);
        acc[1][j][0] = fmaf(a1, v0, acc[1][j][0]);
        acc[1][j][1] = fmaf(a1, v1, acc[1][j][1]);
        acc[2][j][0] = fmaf(a2, v0, acc[2][j][0]);
        acc[2][j][1] = fmaf(a2, v1, acc[2][j][1]);
        acc[3][j][0] = fmaf(a3, v0, acc[3][j][0]);
        acc[3][j][1] = fmaf(a3, v1, acc[3][j][1]);
      }
    }
    __syncthreads();
  }

  // ---- epilogue: out[bc, nd, nh, w], float2 stores, wave writes 1KB contiguous
  float* ob = out + (size_t)bc * 32768;
  #pragma unroll
  for (int i = 0; i < 4; ++i) {
    const int nd = wv * 4 + i;
    #pragma unroll
    for (int j = 0; j < 8; ++j) {
      const int nh = j * 4 + nhq;
      float2 v;
      v.x = acc[i][j][0];
      v.y = acc[i][j][1];
      *(float2*)(ob + nd * 1024 + nh * 32 + w16 * 2) = v;
    }
  }
}

extern "C" void kernel_launch(void* const* d_in, const int* in_sizes, int n_in,
                              void* d_out, int out_size, void* d_ws, size_t ws_size,
                              hipStream_t stream) {
  const float* x = (const float*)d_in[0];
  float* A = (float*)d_ws;          // 32*64 floats
  float* At = A + 2048;             // 64*32 floats
  build_A_kernel<<<2, 1024, 0, stream>>>(A, At);
  spectral_kernel<<<256, 512, 0, stream>>>(x, A, At, (float*)d_out);
}

// Round 3
// 368.327 us; speedup vs baseline: 1.3003x; 1.0390x over previous
//
#include <hip/hip_runtime.h>
#include <math.h>

// SpectralPooling: out[b,c,nd,nh,w] = sum_{d,h} A[nd,d]*A[nh,h]*x[b,c,d,h,w]  (w<32)
// where A = C32^T @ C64[:32,:] (32x64). The B-axis forward+inverse 8-pt DCT is
// C8^T C8 = I (orthonormal) and is skipped exactly.

__global__ void build_A_kernel(float* __restrict__ A, float* __restrict__ At) {
  int idx = blockIdx.x * blockDim.x + threadIdx.x;
  if (idx >= 32 * 64) return;
  int n = idx >> 6;   // 0..31 output freq
  int h = idx & 63;   // 0..63 spatial
  const float s32a = sqrtf(1.0f / 32.0f), s32b = sqrtf(2.0f / 32.0f);
  const float s64a = sqrtf(1.0f / 64.0f), s64b = sqrtf(2.0f / 64.0f);
  float s = 0.0f;
  for (int k = 0; k < 32; ++k) {
    float c32 = cosf((float)M_PI * ((float)n + 0.5f) * (float)k / 32.0f) * ((k == 0) ? s32a : s32b);
    float c64 = cosf((float)M_PI * ((float)h + 0.5f) * (float)k / 64.0f) * ((k == 0) ? s64a : s64b);
    s = fmaf(c32, c64, s);
  }
  A[n * 64 + h] = s;    // A[n][h]  (stage-1 wave-uniform scalar loads)
  At[h * 32 + n] = s;   // At[h][n] (stage-2 wave-uniform scalar loads)
}

// One workgroup per (b,c): 1024 threads = 16 waves, 128 KB LDS -> 1 block/CU,
// 16 waves/CU = 4 waves/SIMD (R2 had only 2/SIMD -> latency-bound, VALUBusy 23%).
// d chunked in 2 halves of 32 -> only 4 __syncthreads total.
// Stage 1: thread -> (dloc = tid>>5, w = tid&31) owns one full x column;
//   h streamed in 16-deep software-pipelined register chunks (loads in flight
//   during 512 FMAs cover ~900cyc HBM latency). A row wave-uniform -> SGPR operand.
// Stage 2: wave wv -> ndg = wv&7 (nd = ndg*4+i), jg = wv>>3 (nh = (jg*4+j)*4+nhq);
//   lane -> (nhq = (tid>>4)&3, w16 = tid&15). float2 LDS reads, 32 FMA / 4 ds_read_b64.
//   Quarter-wave spans banks 0..31 exactly once -> conflict-free, no padding needed.
__global__ __launch_bounds__(1024, 4) void spectral_kernel(
    const float* __restrict__ x, const float* __restrict__ A,
    const float* __restrict__ At, float* __restrict__ out) {
  __shared__ float V[32][32][32];  // 128 KB: [d_in_chunk][nh][w]

  const int tid = threadIdx.x;
  const int bc = blockIdx.x;            // b*32 + c
  const int wv = tid >> 6;              // 0..15 (wave-uniform)
  const int dloc = tid >> 5;            // 0..31 stage-1 d within chunk
  const int w = tid & 31;               // stage-1 w
  const int nhq = (tid >> 4) & 3;       // stage-2 nh sub
  const int w16 = tid & 15;             // stage-2 w pair
  const int ndg = wv & 7;               // stage-2 nd group (wave-uniform)
  const int jg = wv >> 3;               // stage-2 nh half (wave-uniform)

  const float* xb = x + (size_t)bc * 262144;  // 64*64*64

  float acc[4][4][2];                   // [nd i][nh j][w pair] = 32 regs
  #pragma unroll
  for (int i = 0; i < 4; ++i)
    #pragma unroll
    for (int j = 0; j < 4; ++j) {
      acc[i][j][0] = 0.f;
      acc[i][j][1] = 0.f;
    }

  #pragma unroll 1
  for (int cc = 0; cc < 2; ++cc) {
    // ---- stage 1: p[nh] = sum_h A[nh,h] * x[d,h,w]
    const int d = cc * 32 + dloc;
    const float* xcol = xb + (size_t)d * 4096 + w;

    float p[32];
    #pragma unroll
    for (int nh = 0; nh < 32; ++nh) p[nh] = 0.f;

    float cur[16], nxt[16];
    #pragma unroll
    for (int i = 0; i < 16; ++i) cur[i] = xcol[i * 64];

    #pragma unroll 1
    for (int hc = 0; hc < 4; ++hc) {
      if (hc < 3) {
        #pragma unroll
        for (int i = 0; i < 16; ++i) nxt[i] = xcol[(hc * 16 + 16 + i) * 64];
      }
      #pragma unroll
      for (int nh = 0; nh < 32; ++nh) {
        const float* Ar = A + nh * 64 + hc * 16;  // wave-uniform -> s_load
        float s = p[nh];
        #pragma unroll
        for (int i = 0; i < 16; ++i) s = fmaf(Ar[i], cur[i], s);
        p[nh] = s;
      }
      #pragma unroll
      for (int i = 0; i < 16; ++i) cur[i] = nxt[i];
    }

    #pragma unroll
    for (int nh = 0; nh < 32; ++nh) V[dloc][nh][w] = p[nh];
    __syncthreads();

    // ---- stage 2: acc[nd][nh][w] += At[d][nd] * V[d][nh][w]
    #pragma unroll 1
    for (int dd = 0; dd < 32; ++dd) {
      const int dg = cc * 32 + dd;
      const float* Acol = At + dg * 32 + ndg * 4;  // wave-uniform -> s_load_dwordx4
      const float a0 = Acol[0], a1 = Acol[1], a2 = Acol[2], a3 = Acol[3];
      #pragma unroll
      for (int j = 0; j < 4; ++j) {
        const int nh = (jg * 4 + j) * 4 + nhq;
        const float2 v = *(const float2*)&V[dd][nh][w16 * 2];
        acc[0][j][0] = fmaf(a0, v.x, acc[0][j][0]);
        acc[0][j][1] = fmaf(a0, v.y, acc[0][j][1]);
        acc[1][j][0] = fmaf(a1, v.x, acc[1][j][0]);
        acc[1][j][1] = fmaf(a1, v.y, acc[1][j][1]);
        acc[2][j][0] = fmaf(a2, v.x, acc[2][j][0]);
        acc[2][j][1] = fmaf(a2, v.y, acc[2][j][1]);
        acc[3][j][0] = fmaf(a3, v.x, acc[3][j][0]);
        acc[3][j][1] = fmaf(a3, v.y, acc[3][j][1]);
      }
    }
    __syncthreads();
  }

  // ---- epilogue: out[bc, nd, nh, w]; each (i,j) store instr covers 512 B contiguous
  float* ob = out + (size_t)bc * 32768;
  #pragma unroll
  for (int i = 0; i < 4; ++i) {
    const int nd = ndg * 4 + i;
    #pragma unroll
    for (int j = 0; j < 4; ++j) {
      const int nh = (jg * 4 + j) * 4 + nhq;
      float2 v;
      v.x = acc[i][j][0];
      v.y = acc[i][j][1];
      *(float2*)(ob + nd * 1024 + nh * 32 + w16 * 2) = v;
    }
  }
}

extern "C" void kernel_launch(void* const* d_in, const int* in_sizes, int n_in,
                              void* d_out, int out_size, void* d_ws, size_t ws_size,
                              hipStream_t stream) {
  const float* x = (const float*)d_in[0];
  float* A = (float*)d_ws;          // 32*64 floats
  float* At = A + 2048;             // 64*32 floats
  build_A_kernel<<<32, 64, 0, stream>>>(A, At);
  spectral_kernel<<<256, 1024, 0, stream>>>(x, A, At, (float*)d_out);
}

// Round 4
// 344.886 us; speedup vs baseline: 1.3887x; 1.0680x over previous
//
#include <hip/hip_runtime.h>

// SpectralPooling: out[b,c,nd,nh,w] = sum_{d,h} A[nd,d]*A[nh,h]*x[b,c,d,h,w]  (w<32)
// where A = C32^T @ C64[:32,:] (32x64). The B-axis forward+inverse 8-pt DCT is
// C8^T C8 = I (orthonormal) and is skipped exactly.
//
// R4: A is a COMPILE-TIME constant table. Stage 1 is fully unrolled so every
// A element folds into the FMA as a 32-bit literal (v_fmamk_f32) -> zero
// scalar loads in the stage-1 hot loop (R1-R3 stalled ~75% on per-iteration
// s_load latency). Stage-2 At is wave-runtime-indexed, so it stays in memory
// but is reordered contiguous-per-wave and batched via unroll-8.

// ---------- compile-time DCT-product table ----------
constexpr double kPI = 3.14159265358979323846;

constexpr double cos_poly(double x) {  // |x| <= pi, ~1e-16
  double r = 1.0;
  for (int k = 15; k >= 1; --k) r = 1.0 - r * x * x / ((2.0 * k) * (2.0 * k - 1.0));
  return r;
}
constexpr double csqrt(double v) {
  double r = (v > 1.0) ? v : 1.0;
  for (int i = 0; i < 64; ++i) r = 0.5 * (r + v / r);
  return r;
}

struct C64T  { double c[128]; };
struct C128T { double c[256]; };
constexpr C64T make_c64() {   // c[m] = cos(pi*m/64), integer-exact reduction
  C64T t{};
  for (int m = 0; m < 128; ++m) {
    int mm = (m > 64) ? m - 128 : m;
    t.c[m] = cos_poly(kPI * (double)mm / 64.0);
  }
  return t;
}
constexpr C128T make_c128() {  // c[m] = cos(pi*m/128)
  C128T t{};
  for (int m = 0; m < 256; ++m) {
    int mm = (m > 128) ? m - 256 : m;
    t.c[m] = cos_poly(kPI * (double)mm / 128.0);
  }
  return t;
}
constexpr C64T  C64_  = make_c64();
constexpr C128T C128_ = make_c128();

struct ATabH { float a[16 * 64]; };  // split in halves: constexpr step budget
constexpr ATabH make_A_half(int n0) {
  ATabH t{};
  const double s32a = csqrt(1.0 / 32.0), s32b = csqrt(2.0 / 32.0);
  const double s64a = csqrt(1.0 / 64.0), s64b = csqrt(2.0 / 64.0);
  for (int ni = 0; ni < 16; ++ni)
    for (int h = 0; h < 64; ++h) {
      const int n = n0 + ni;
      double s = 0.0;
      for (int k = 0; k < 32; ++k) {
        double sc = ((k == 0) ? s32a : s32b) * ((k == 0) ? s64a : s64b);
        s += sc * C64_.c[((2 * n + 1) * k) % 128] * C128_.c[((2 * h + 1) * k) % 256];
      }
      t.a[ni * 64 + h] = (float)s;
    }
  return t;
}
constexpr ATabH A_LO = make_A_half(0);
constexpr ATabH A_HI = make_A_half(16);

__host__ __device__ constexpr float Aval(int n, int h) {  // folds after unroll
  return (n < 16) ? A_LO.a[n * 64 + h] : A_HI.a[(n - 16) * 64 + h];
}

// Stage-2 table, reordered so each wave's per-chunk slice is contiguous:
// AT2[ndg][dg][i] = A[ndg*4+i][dg]   (ndg = wave's nd group)
struct AT2Tab { float a[8 * 64 * 4]; };
constexpr AT2Tab make_AT2() {
  AT2Tab t{};
  for (int ndg = 0; ndg < 8; ++ndg)
    for (int dg = 0; dg < 64; ++dg)
      for (int i = 0; i < 4; ++i)
        t.a[(ndg * 64 + dg) * 4 + i] = Aval(ndg * 4 + i, dg);
  return t;
}
__device__ const AT2Tab AT2_DEV = make_AT2();  // runtime wave-indexed -> s_load

// ---------- stage-1 helper: 16 h-steps, fully unrolled, A as literals ----------
template <int HB>
__device__ __forceinline__ void s1_group(float (&p)[32], const float (&xr)[16]) {
#pragma unroll
  for (int nh = 0; nh < 32; ++nh) {
    float s = p[nh];
#pragma unroll
    for (int i = 0; i < 16; ++i) s = fmaf(Aval(nh, HB + i), xr[i], s);
    p[nh] = s;
  }
}

// One workgroup per (b,c): 1024 threads = 16 waves, 135 KB LDS -> 1 block/CU.
// Stage 1: thread (dloc = tid>>5, w = tid&31) owns one x column; h in 4
//   pipelined groups of 16 (16 coalesced dword loads in flight per group).
// Stage 2: wave -> (ndg = wv&7, jg = wv>>3), lane -> (nhq, w16); float2 LDS
//   reads (V padded to 33 -> 2-way max bank aliasing), acc[4 nd][4 nh][2 w].
__global__ __launch_bounds__(1024, 4) void spectral_kernel(
    const float* __restrict__ x, float* __restrict__ out) {
  __shared__ float V[32][32][33];  // 135 KB: [d_in_chunk][nh][w + pad]

  const int tid = threadIdx.x;
  const int bc = blockIdx.x;            // b*32 + c
  const int wv = tid >> 6;              // 0..15 (wave-uniform)
  const int dloc = tid >> 5;            // 0..31 stage-1 d within chunk
  const int w = tid & 31;               // stage-1 w
  const int nhq = (tid >> 4) & 3;       // stage-2 nh sub
  const int w16 = tid & 15;             // stage-2 w pair
  const int ndg = wv & 7;               // stage-2 nd group (wave-uniform)
  const int jg = wv >> 3;               // stage-2 nh half (wave-uniform)

  const float* xb = x + (size_t)bc * 262144;  // 64*64*64

  float acc[4][4][2];
#pragma unroll
  for (int i = 0; i < 4; ++i)
#pragma unroll
    for (int j = 0; j < 4; ++j) {
      acc[i][j][0] = 0.f;
      acc[i][j][1] = 0.f;
    }

#pragma unroll 1
  for (int cc = 0; cc < 2; ++cc) {
    // ---- stage 1: p[nh] = sum_h A[nh,h]*x[d,h,w]; pure v_fmamk, no A loads
    const int d = cc * 32 + dloc;
    const float* xcol = xb + (size_t)d * 4096 + w;

    float p[32];
#pragma unroll
    for (int nh = 0; nh < 32; ++nh) p[nh] = 0.f;

    float xa[16], xc[16];
#pragma unroll
    for (int i = 0; i < 16; ++i) xa[i] = xcol[i * 64];
#pragma unroll
    for (int i = 0; i < 16; ++i) xc[i] = xcol[(16 + i) * 64];
    s1_group<0>(p, xa);
#pragma unroll
    for (int i = 0; i < 16; ++i) xa[i] = xcol[(32 + i) * 64];
    s1_group<16>(p, xc);
#pragma unroll
    for (int i = 0; i < 16; ++i) xc[i] = xcol[(48 + i) * 64];
    s1_group<32>(p, xa);
    s1_group<48>(p, xc);

#pragma unroll
    for (int nh = 0; nh < 32; ++nh) V[dloc][nh][w] = p[nh];
    __syncthreads();

    // ---- stage 2: acc[nd][nh][w] += A[nd,d] * V[d][nh][w]
    const float4* at4 = (const float4*)(AT2_DEV.a) + ndg * 64 + cc * 32;
#pragma unroll 8
    for (int dd = 0; dd < 32; ++dd) {
      const float4 a4 = at4[dd];  // wave-uniform s_load_dwordx4, batched x8
#pragma unroll
      for (int j = 0; j < 4; ++j) {
        const int nh = (jg * 4 + j) * 4 + nhq;
        const float2 v = *(const float2*)&V[dd][nh][w16 * 2];
        acc[0][j][0] = fmaf(a4.x, v.x, acc[0][j][0]);
        acc[0][j][1] = fmaf(a4.x, v.y, acc[0][j][1]);
        acc[1][j][0] = fmaf(a4.y, v.x, acc[1][j][0]);
        acc[1][j][1] = fmaf(a4.y, v.y, acc[1][j][1]);
        acc[2][j][0] = fmaf(a4.z, v.x, acc[2][j][0]);
        acc[2][j][1] = fmaf(a4.z, v.y, acc[2][j][1]);
        acc[3][j][0] = fmaf(a4.w, v.x, acc[3][j][0]);
        acc[3][j][1] = fmaf(a4.w, v.y, acc[3][j][1]);
      }
    }
    __syncthreads();
  }

  // ---- epilogue: out[bc, nd, nh, w]; each (i,j) store covers 512 B contiguous
  float* ob = out + (size_t)bc * 32768;
#pragma unroll
  for (int i = 0; i < 4; ++i) {
    const int nd = ndg * 4 + i;
#pragma unroll
    for (int j = 0; j < 4; ++j) {
      const int nh = (jg * 4 + j) * 4 + nhq;
      float2 v;
      v.x = acc[i][j][0];
      v.y = acc[i][j][1];
      *(float2*)(ob + nd * 1024 + nh * 32 + w16 * 2) = v;
    }
  }
}

extern "C" void kernel_launch(void* const* d_in, const int* in_sizes, int n_in,
                              void* d_out, int out_size, void* d_ws, size_t ws_size,
                              hipStream_t stream) {
  const float* x = (const float*)d_in[0];
  spectral_kernel<<<256, 1024, 0, stream>>>(x, (float*)d_out);
}